// Round 16
// baseline (719.355 us; speedup 1.0000x reference)
//
#include <hip/hip_runtime.h>
#include <math.h>

// Problem constants (MinimalGPT)
#define V_SZ 32000
#define D_SZ 512
#define NL 4
#define NH 8
#define SEQ 2048
#define HD 64
#define NB 2
#define M_ROWS (NB * SEQ)   // 4096

typedef __attribute__((ext_vector_type(8))) short bf16x8;
typedef __attribute__((ext_vector_type(4))) float f32x4;
typedef __attribute__((ext_vector_type(4))) unsigned short u16x4;

__device__ __forceinline__ unsigned short f2bf(float f) {
    unsigned int x = __float_as_uint(f);
    unsigned int r = (x + 0x7FFFu + ((x >> 16) & 1u)) >> 16;
    return (unsigned short)r;
}

__device__ __forceinline__ float gelu_f(float x) {
    return 0.5f * x * (1.0f + erff(x * 0.70710678118654752f));
}

__device__ __forceinline__ void gload16(const void* g, void* l) {
    __builtin_amdgcn_global_load_lds(
        (const __attribute__((address_space(1))) void*)g,
        (__attribute__((address_space(3))) void*)l, 16, 0, 0);
}

// ---------------- merged prep: 4x tconv (weights->bf16 [N,K]) + embedding -----
__device__ __forceinline__ void tconv_body(
    const float* __restrict__ in, unsigned short* __restrict__ out,
    int K, int N, int lin, float (*t)[33]) {
    int nx = N / 32, ny = K / 32;
    int bx = lin % nx;
    int r2 = lin / nx;
    int by = r2 % ny;
    int l = r2 / ny;
    in += (size_t)l * K * N;
    out += (size_t)l * N * K;
    int n0 = bx * 32, k0 = by * 32;
    int tx = threadIdx.x & 31, ty = threadIdx.x >> 5;
    #pragma unroll
    for (int p = 0; p < 4; p++) {
        int k = ty + p * 8;
        t[k][tx] = in[(size_t)(k0 + k) * N + n0 + tx];
    }
    __syncthreads();
    #pragma unroll
    for (int p = 0; p < 4; p++) {
        int n = ty + p * 8;
        out[(size_t)(n0 + n) * K + k0 + tx] = f2bf(t[tx][n]);
    }
}

#define TCQ 3072   // (1536/32)*(512/32)*4
#define TCP 1024   // (512/32)*(512/32)*4
#define TC1 4096   // (2048/32)*(512/32)*4
#define TC2 4096   // (512/32)*(2048/32)*4
#define EMB 8192   // 4096*512/256

__global__ __launch_bounds__(256) void prep_kernel(
    const float* __restrict__ qkvw, const float* __restrict__ projw,
    const float* __restrict__ fc1w, const float* __restrict__ fc2w,
    const int* __restrict__ ids, const float* __restrict__ tok,
    const float* __restrict__ pos,
    unsigned short* __restrict__ wq, unsigned short* __restrict__ wp,
    unsigned short* __restrict__ w1, unsigned short* __restrict__ w2,
    float* __restrict__ x) {
    __shared__ float t[32][33];
    int b = blockIdx.x;
    if (b < TCQ) { tconv_body(qkvw, wq, D_SZ, 3 * D_SZ, b, t); return; }
    b -= TCQ;
    if (b < TCP) { tconv_body(projw, wp, D_SZ, D_SZ, b, t); return; }
    b -= TCP;
    if (b < TC1) { tconv_body(fc1w, w1, D_SZ, 4 * D_SZ, b, t); return; }
    b -= TC1;
    if (b < TC2) { tconv_body(fc2w, w2, 4 * D_SZ, D_SZ, b, t); return; }
    b -= TC2;
    // embedding
    int idx = b * 256 + threadIdx.x;
    int row = idx >> 9;
    int d = idx & 511;
    int tt = row & (SEQ - 1);
    x[idx] = tok[(size_t)ids[row] * D_SZ + d] + pos[(size_t)tt * D_SZ + d];
}

// ---------------- layernorm over last dim (512) -> bf16 out --------------------
// wave-per-row: 4 waves/block, one row per wave, pure shfl reduce.
__global__ __launch_bounds__(256) void ln_kernel(
    const float* __restrict__ x, const float* __restrict__ w,
    const float* __restrict__ b, unsigned short* __restrict__ out) {
    int row = blockIdx.x * 4 + (threadIdx.x >> 6);
    int lane = threadIdx.x & 63;
    const float* xr = x + (size_t)row * D_SZ + lane * 8;
    float4 v0 = *(const float4*)xr;
    float4 v1 = *(const float4*)(xr + 4);
    float s = ((v0.x + v0.y) + (v0.z + v0.w)) + ((v1.x + v1.y) + (v1.z + v1.w));
    #pragma unroll
    for (int off = 1; off < 64; off <<= 1) s += __shfl_xor(s, off);
    float mu = s * (1.0f / 512.0f);
    float d0 = v0.x - mu, d1 = v0.y - mu, d2 = v0.z - mu, d3 = v0.w - mu;
    float d4 = v1.x - mu, d5 = v1.y - mu, d6 = v1.z - mu, d7 = v1.w - mu;
    float q = ((d0 * d0 + d1 * d1) + (d2 * d2 + d3 * d3)) +
              ((d4 * d4 + d5 * d5) + (d6 * d6 + d7 * d7));
    #pragma unroll
    for (int off = 1; off < 64; off <<= 1) q += __shfl_xor(q, off);
    float rs = rsqrtf(q * (1.0f / 512.0f) + 1e-5f);
    const float* wp = w + lane * 8;
    const float* bp = b + lane * 8;
    float4 w0 = *(const float4*)wp, w1 = *(const float4*)(wp + 4);
    float4 b0 = *(const float4*)bp, b1 = *(const float4*)(bp + 4);
    uint4 pk;
    pk.x = (unsigned)f2bf(d0 * rs * w0.x + b0.x) | ((unsigned)f2bf(d1 * rs * w0.y + b0.y) << 16);
    pk.y = (unsigned)f2bf(d2 * rs * w0.z + b0.z) | ((unsigned)f2bf(d3 * rs * w0.w + b0.w) << 16);
    pk.z = (unsigned)f2bf(d4 * rs * w1.x + b1.x) | ((unsigned)f2bf(d5 * rs * w1.y + b1.y) << 16);
    pk.w = (unsigned)f2bf(d6 * rs * w1.z + b1.z) | ((unsigned)f2bf(d7 * rs * w1.w + b1.w) << 16);
    *(uint4*)(out + (size_t)row * D_SZ + lane * 8) = pk;
}

// ---------------- merged final-LN (wave-per-row) + tok_emb conv (NT) ----------
__global__ __launch_bounds__(256) void lnconv_kernel(
    const float* __restrict__ x, const float* __restrict__ w,
    const float* __restrict__ b, unsigned short* __restrict__ out,
    const float* __restrict__ tok, unsigned short* __restrict__ tokb) {
    int blk = blockIdx.x;
    if (blk < M_ROWS / 4) {
        int row = blk * 4 + (threadIdx.x >> 6);
        int lane = threadIdx.x & 63;
        const float* xr = x + (size_t)row * D_SZ + lane * 8;
        float4 v0 = *(const float4*)xr;
        float4 v1 = *(const float4*)(xr + 4);
        float s = ((v0.x + v0.y) + (v0.z + v0.w)) + ((v1.x + v1.y) + (v1.z + v1.w));
        #pragma unroll
        for (int off = 1; off < 64; off <<= 1) s += __shfl_xor(s, off);
        float mu = s * (1.0f / 512.0f);
        float d0 = v0.x - mu, d1 = v0.y - mu, d2 = v0.z - mu, d3 = v0.w - mu;
        float d4 = v1.x - mu, d5 = v1.y - mu, d6 = v1.z - mu, d7 = v1.w - mu;
        float q = ((d0 * d0 + d1 * d1) + (d2 * d2 + d3 * d3)) +
                  ((d4 * d4 + d5 * d5) + (d6 * d6 + d7 * d7));
        #pragma unroll
        for (int off = 1; off < 64; off <<= 1) q += __shfl_xor(q, off);
        float rs = rsqrtf(q * (1.0f / 512.0f) + 1e-5f);
        const float* wp = w + lane * 8;
        const float* bp = b + lane * 8;
        float4 w0 = *(const float4*)wp, w1 = *(const float4*)(wp + 4);
        float4 b0 = *(const float4*)bp, b1 = *(const float4*)(bp + 4);
        uint4 pk;
        pk.x = (unsigned)f2bf(d0 * rs * w0.x + b0.x) | ((unsigned)f2bf(d1 * rs * w0.y + b0.y) << 16);
        pk.y = (unsigned)f2bf(d2 * rs * w0.z + b0.z) | ((unsigned)f2bf(d3 * rs * w0.w + b0.w) << 16);
        pk.z = (unsigned)f2bf(d4 * rs * w1.x + b1.x) | ((unsigned)f2bf(d5 * rs * w1.y + b1.y) << 16);
        pk.w = (unsigned)f2bf(d6 * rs * w1.z + b1.z) | ((unsigned)f2bf(d7 * rs * w1.w + b1.w) << 16);
        *(uint4*)(out + (size_t)row * D_SZ + lane * 8) = pk;
    } else {
        int i = (blk - M_ROWS / 4) * 256 + threadIdx.x;
        float4 v = ((const float4*)tok)[i];
        u16x4 u;
        u.x = f2bf(v.x); u.y = f2bf(v.y); u.z = f2bf(v.z); u.w = f2bf(v.w);
        __builtin_nontemporal_store(u, (u16x4*)tokb + i);
    }
}

// ---------------- MFMA flash attention (bf16 in/out, f32 softmax) --------------
// R12 version: T14 reg prefetch; Q pre-scaled by 0.125 (exact pow2).
__global__ __launch_bounds__(256) void mattn_kernel(
    const unsigned short* __restrict__ qkv, unsigned short* __restrict__ att) {
    __shared__ unsigned short Ks[64][72];       // [key][dim], +8 pad
    __shared__ unsigned short Vt[64][72];       // [dim][key], block-swizzled
    __shared__ unsigned short Ps[4][16][72];    // per-wave [q][key]
    int id = blockIdx.x;
    int bh = id >> 5;
    int jraw = id & 31;
    int jt = (id < 256) ? jraw : (31 - jraw);   // heavy/light pairing
    int b = bh >> 3, h = bh & 7;
    int tid = threadIdx.x, lane = tid & 63, wid = tid >> 6;
    int q15 = lane & 15, g = lane >> 4;
    int qglob = jt * 64 + wid * 16 + q15;       // this lane's q row (in batch b)
    const unsigned short* base = qkv + (size_t)b * SEQ * (3 * D_SZ);
    const unsigned short* qptr = base + (size_t)qglob * (3 * D_SZ) + h * HD;
    bf16x8 qf0 = *(const bf16x8*)(qptr + g * 8);
    bf16x8 qf1 = *(const bf16x8*)(qptr + 32 + g * 8);
    // pre-scale Q by 1/sqrt(HD)=0.125 (exact for bf16: power-of-2)
    #pragma unroll
    for (int i = 0; i < 8; i++) {
        qf0[i] = (short)f2bf(
            __uint_as_float(((unsigned)(unsigned short)qf0[i]) << 16) * 0.125f);
        qf1[i] = (short)f2bf(
            __uint_as_float(((unsigned)(unsigned short)qf1[i]) << 16) * 0.125f);
    }

    f32x4 OT[4];
    f32x4 zero = {0.0f, 0.0f, 0.0f, 0.0f};
    #pragma unroll
    for (int n = 0; n < 4; n++) OT[n] = zero;
    float mrun = -1e30f, lrun = 0.0f;

    // prefetch lanes/addresses
    int krow = tid >> 3, kprt = tid & 7;        // K: rows krow and 32+krow
    const unsigned short* kbase = base + D_SZ + h * HD + kprt * 8;
    const unsigned short* vbase = base + 2 * D_SZ + h * HD + kprt * 8;
    bf16x8 kp0, kp1, vp0, vp1;

    // prologue: load tile 0 into regs
    kp0 = *(const bf16x8*)(kbase + (size_t)krow * (3 * D_SZ));
    kp1 = *(const bf16x8*)(kbase + (size_t)(32 + krow) * (3 * D_SZ));
    vp0 = *(const bf16x8*)(vbase + (size_t)(2 * krow) * (3 * D_SZ));
    vp1 = *(const bf16x8*)(vbase + (size_t)(2 * krow + 1) * (3 * D_SZ));

    int nt = jt + 1;
    for (int st = 0; st < nt; st++) {
        int s0 = st * 64;
        __syncthreads();                        // prev-tile consumers done
        // write prefetched K [key][dim]
        *(bf16x8*)&Ks[krow][kprt * 8] = kp0;
        *(bf16x8*)&Ks[32 + krow][kprt * 8] = kp1;
        // write prefetched V^T [dim][key] with block swizzle
        {
            int col = (((krow >> 2) ^ kprt) << 3) | ((2 * krow) & 7);
            #pragma unroll
            for (int i = 0; i < 8; i++) {
                int d = kprt * 8 + i;
                unsigned w = (unsigned)(unsigned short)vp0[i]
                           | ((unsigned)(unsigned short)vp1[i] << 16);
                *(unsigned*)&Vt[d][col] = w;
            }
        }
        __syncthreads();
        // issue next-tile loads (latency overlaps compute below)
        if (st + 1 < nt) {
            int s1 = s0 + 64;
            kp0 = *(const bf16x8*)(kbase + (size_t)(s1 + krow) * (3 * D_SZ));
            kp1 = *(const bf16x8*)(kbase + (size_t)(s1 + 32 + krow) * (3 * D_SZ));
            vp0 = *(const bf16x8*)(vbase + (size_t)(s1 + 2 * krow) * (3 * D_SZ));
            vp1 = *(const bf16x8*)(vbase + (size_t)(s1 + 2 * krow + 1) * (3 * D_SZ));
        }

        // S^T = K @ Q^T : frag n covers keys n*16..+15 (Q pre-scaled)
        f32x4 S[4];
        #pragma unroll
        for (int n = 0; n < 4; n++) S[n] = zero;
        #pragma unroll
        for (int n = 0; n < 4; n++)
            S[n] = __builtin_amdgcn_mfma_f32_16x16x32_bf16(
                *(const bf16x8*)&Ks[n * 16 + q15][g * 8], qf0, S[n], 0, 0, 0);
        #pragma unroll
        for (int n = 0; n < 4; n++)
            S[n] = __builtin_amdgcn_mfma_f32_16x16x32_bf16(
                *(const bf16x8*)&Ks[n * 16 + q15][32 + g * 8], qf1, S[n], 0, 0, 0);

        // softmax (per lane: 16 scores of q-row qglob; keys n*16+g*4+r)
        bool diag = (st == jt);
        float sm[4][4];
        float mloc = -1e30f;
        #pragma unroll
        for (int n = 0; n < 4; n++)
            #pragma unroll
            for (int r = 0; r < 4; r++) {
                float s = S[n][r];
                if (diag && (s0 + n * 16 + g * 4 + r) > qglob) s = -1e30f;
                sm[n][r] = s;
                mloc = fmaxf(mloc, s);
            }
        mloc = fmaxf(mloc, __shfl_xor(mloc, 16));
        mloc = fmaxf(mloc, __shfl_xor(mloc, 32));
        float mnew = fmaxf(mrun, mloc);
        float corr = __expf(mrun - mnew);
        lrun *= corr;
        #pragma unroll
        for (int n = 0; n < 4; n++) OT[n] *= corr;
        float lsum = 0.0f;
        #pragma unroll
        for (int n = 0; n < 4; n++) {
            float p0 = __expf(sm[n][0] - mnew);
            float p1 = __expf(sm[n][1] - mnew);
            float p2 = __expf(sm[n][2] - mnew);
            float p3 = __expf(sm[n][3] - mnew);
            lsum += (p0 + p1) + (p2 + p3);
            uint2 pk;
            pk.x = (unsigned)f2bf(p0) | ((unsigned)f2bf(p1) << 16);
            pk.y = (unsigned)f2bf(p2) | ((unsigned)f2bf(p3) << 16);
            *(uint2*)&Ps[wid][q15][n * 16 + g * 4] = pk;
        }
        lsum += __shfl_xor(lsum, 16);
        lsum += __shfl_xor(lsum, 32);
        lrun += lsum;
        mrun = mnew;

        // O^T += V^T @ P^T : frag n covers dims n*16..+15
        #pragma unroll
        for (int ks = 0; ks < 2; ks++) {
            bf16x8 bp = *(const bf16x8*)&Ps[wid][q15][ks * 32 + g * 8];
            #pragma unroll
            for (int n = 0; n < 4; n++) {
                int d = n * 16 + q15;
                int col = (((ks * 4 + g) ^ ((d >> 3) & 7)) << 3);
                OT[n] = __builtin_amdgcn_mfma_f32_16x16x32_bf16(
                    *(const bf16x8*)&Vt[d][col], bp, OT[n], 0, 0, 0);
            }
        }
    }

    float inv = 1.0f / lrun;
    unsigned short* orow = att + ((size_t)(b * SEQ) + qglob) * D_SZ + h * HD;
    #pragma unroll
    for (int n = 0; n < 4; n++) {
        uint2 u;
        u.x = (unsigned)f2bf(OT[n][0] * inv) | ((unsigned)f2bf(OT[n][1] * inv) << 16);
        u.y = (unsigned)f2bf(OT[n][2] * inv) | ((unsigned)f2bf(OT[n][3] * inv) << 16);
        *(uint2*)(orow + n * 16 + g * 4) = u;
    }
}

// ---------------- bf16 MFMA GEMM: C = A[M,K] @ Bt[N,K]^T (+bias)(+gelu)(+resid)
// 2-phase double-buffered K-loop (session-best structure). SWAPXY: head grid
// sweeps M fastest (B-panel L2 locality, R5 win). NTC: non-temporal scalar
// C-stores, row-outer/col-inner order (R10+R12: 694us verified).
// XCDSWZ (R15, head only): bijective XCD-chunk swizzle — without it every
// B-panel is pulled into all 8 XCD L2s (~262MB L2-fill); with it each XCD owns
// ~31 contiguous panels (~33MB total fill). nwg=8000 divisible by 8.
template <int BM, int BN, int BK, int WC, bool BIAS, bool GELU_, bool RESID,
          bool OUTBF, bool SWAPXY, bool NTC, bool XCDSWZ>
__global__ __launch_bounds__(256) void mgemm_kernel(
    const unsigned short* __restrict__ A,    // [M,K] bf16
    const unsigned short* __restrict__ Bt,   // [N,K] bf16
    const float* __restrict__ bias,
    const float* __restrict__ resid,
    void* __restrict__ Cv, int M, int N, int K) {
    constexpr int WR = 4 / WC;
    constexpr int WRM = BM / WR;
    constexpr int WCN = BN / WC;
    constexpr int FM = WRM / 16;
    constexpr int FN = WCN / 16;
    constexpr int CPR = BK / 8;            // 16B chunks per LDS row
    constexpr int LA = BM * CPR / 256;     // A chunks per thread
    constexpr int LB = BN * CPR / 256;     // B chunks per thread
    __shared__ __attribute__((aligned(16))) unsigned short As[2][BM][BK];
    __shared__ __attribute__((aligned(16))) unsigned short Bs[2][BN][BK];
    int tid = threadIdx.x;
    int lane = tid & 63;
    int wid = tid >> 6;
    int wr = wid / WC, wc = wid % WC;
    int bx = blockIdx.x, by = blockIdx.y;
    if (XCDSWZ) {
        int gx = gridDim.x;
        int nwg = gx * gridDim.y;            // must be divisible by 8
        int lin = by * gx + bx;
        int cpx = nwg >> 3;
        int swz = (lin & 7) * cpx + (lin >> 3);
        bx = swz % gx;
        by = swz / gx;
    }
    int m0 = (SWAPXY ? bx : by) * BM;
    int n0 = (SWAPXY ? by : bx) * BN;
    int r16 = lane & 15, kg = lane >> 4;

    f32x4 acc[FM][FN];
    f32x4 zero = {0.0f, 0.0f, 0.0f, 0.0f};
    #pragma unroll
    for (int m = 0; m < FM; m++)
        #pragma unroll
        for (int n = 0; n < FN; n++) acc[m][n] = zero;

    const unsigned short* Abase = A + (size_t)m0 * K;
    const unsigned short* Bbase = Bt + (size_t)n0 * K;

    // prologue: stage K-tile 0 into buffer 0
    #pragma unroll
    for (int i = 0; i < LA; i++) {
        int c = i * 256 + tid;
        gload16(Abase + (size_t)(c / CPR) * K + (c % CPR) * 8,
                &As[0][c / CPR][(c % CPR) * 8]);
    }
    #pragma unroll
    for (int i = 0; i < LB; i++) {
        int c = i * 256 + tid;
        gload16(Bbase + (size_t)(c / CPR) * K + (c % CPR) * 8,
                &Bs[0][c / CPR][(c % CPR) * 8]);
    }
    __syncthreads();

    unsigned short* a_cur = &As[0][0][0];
    unsigned short* a_nxt = &As[1][0][0];
    unsigned short* b_cur = &Bs[0][0][0];
    unsigned short* b_nxt = &Bs[1][0][0];

    for (int k0 = 0; k0 < K; k0 += BK) {
        // issue next-tile staging first (overlaps with current compute)
        if (k0 + BK < K) {
            #pragma unroll
            for (int i = 0; i < LA; i++) {
                int c = i * 256 + tid;
                gload16(Abase + (size_t)(c / CPR) * K + (k0 + BK) + (c % CPR) * 8,
                        a_nxt + c * 8);
            }
            #pragma unroll
            for (int i = 0; i < LB; i++) {
                int c = i * 256 + tid;
                gload16(Bbase + (size_t)(c / CPR) * K + (k0 + BK) + (c % CPR) * 8,
                        b_nxt + c * 8);
            }
        }
        #pragma unroll
        for (int kk = 0; kk < BK / 32; kk++) {
            bf16x8 af[FM], bfr[FN];
            #pragma unroll
            for (int m = 0; m < FM; m++)
                af[m] = *(const bf16x8*)&a_cur[(wr * WRM + m * 16 + r16) * BK +
                                               kk * 32 + kg * 8];
            #pragma unroll
            for (int n = 0; n < FN; n++)
                bfr[n] = *(const bf16x8*)&b_cur[(wc * WCN + n * 16 + r16) * BK +
                                                kk * 32 + kg * 8];
            #pragma unroll
            for (int m = 0; m < FM; m++)
                #pragma unroll
                for (int n = 0; n < FN; n++)
                    acc[m][n] = __builtin_amdgcn_mfma_f32_16x16x32_bf16(
                        af[m], bfr[n], acc[m][n], 0, 0, 0);
        }
        __syncthreads();   // vmcnt(0)+lgkmcnt(0) drain AFTER compute
        unsigned short* t;
        t = a_cur; a_cur = a_nxt; a_nxt = t;
        t = b_cur; b_cur = b_nxt; b_nxt = t;
    }

    // epilogue: row-outer / col-inner store order (write-combining friendly)
    float bvv[FN];
    #pragma unroll
    for (int n = 0; n < FN; n++)
        bvv[n] = BIAS ? bias[n0 + wc * WCN + n * 16 + r16] : 0.0f;
    #pragma unroll
    for (int m = 0; m < FM; m++) {
        int rb = m0 + wr * WRM + m * 16 + kg * 4;
        #pragma unroll
        for (int r = 0; r < 4; r++) {
            size_t rowoff = (size_t)(rb + r) * N;
            #pragma unroll
            for (int n = 0; n < FN; n++) {
                int col = n0 + wc * WCN + n * 16 + r16;
                float v = acc[m][n][r] + bvv[n];
                if (GELU_) v = gelu_f(v);
                if (RESID) v += resid[rowoff + col];
                if (OUTBF) {
                    ((unsigned short*)Cv)[rowoff + col] = f2bf(v);
                } else if (NTC) {
                    __builtin_nontemporal_store(v, (float*)Cv + rowoff + col);
                } else {
                    ((float*)Cv)[rowoff + col] = v;
                }
            }
        }
    }
}

extern "C" void kernel_launch(void* const* d_in, const int* in_sizes, int n_in,
                              void* d_out, int out_size, void* d_ws, size_t ws_size,
                              hipStream_t stream) {
    const int*   ids   = (const int*)d_in[0];
    const float* tok   = (const float*)d_in[1];
    const float* pos   = (const float*)d_in[2];
    const float* ln1w  = (const float*)d_in[3];
    const float* ln1b  = (const float*)d_in[4];
    const float* qkvw  = (const float*)d_in[5];
    const float* qkvb  = (const float*)d_in[6];
    const float* projw = (const float*)d_in[7];
    const float* projb = (const float*)d_in[8];
    const float* ln2w  = (const float*)d_in[9];
    const float* ln2b  = (const float*)d_in[10];
    const float* fc1w  = (const float*)d_in[11];
    const float* fc1b  = (const float*)d_in[12];
    const float* fc2w  = (const float*)d_in[13];
    const float* fc2b  = (const float*)d_in[14];
    const float* lnfw  = (const float*)d_in[15];
    const float* lnfb  = (const float*)d_in[16];
    float* out = (float*)d_out;

    // ws layout:
    float* x = (float*)d_ws;                                   // [4096,512] f32
    unsigned short* hb = (unsigned short*)(x + (size_t)M_ROWS * D_SZ);
    unsigned short* wq = hb + (size_t)M_ROWS * D_SZ;           // [4][1536,512]
    unsigned short* wp = wq + (size_t)NL * D_SZ * 3 * D_SZ;    // [4][512,512]
    unsigned short* w1 = wp + (size_t)NL * D_SZ * D_SZ;        // [4][2048,512]
    unsigned short* w2 = w1 + (size_t)NL * D_SZ * 4 * D_SZ;    // [4][512,2048]
    unsigned short* qkvb_a = w2 + (size_t)NL * 4 * D_SZ * D_SZ;// [4096,1536] bf16
    unsigned short* attb = qkvb_a + (size_t)M_ROWS * 3 * D_SZ; // [4096,512]
    unsigned short* ffnb = attb + (size_t)M_ROWS * D_SZ;       // [4096,2048]
    unsigned short* tokb = qkvb_a;   // [32000,512] aliases qkv+attb+ffnb (33.4MB)

    // merged prep: 4x weight tconv + embedding (1 dispatch instead of 5)
    prep_kernel<<<TCQ + TCP + TC1 + TC2 + EMB, 256, 0, stream>>>(
        qkvw, projw, fc1w, fc2w, ids, tok, pos, wq, wp, w1, w2, x);

    for (int l = 0; l < NL; l++) {
        ln_kernel<<<M_ROWS / 4, 256, 0, stream>>>(x, ln1w + l * D_SZ, ln1b + l * D_SZ, hb);
        // qkv = hb @ qkv_w + b   [4096,1536] bf16   (64x128x64: 768 blk = 3/CU)
        mgemm_kernel<64, 128, 64, 2, true, false, false, true, false, false, false>
            <<<dim3(3 * D_SZ / 128, M_ROWS / 64), 256, 0, stream>>>(
                hb, wq + (size_t)l * 3 * D_SZ * D_SZ, qkvb + (size_t)l * 3 * D_SZ,
                nullptr, qkvb_a, M_ROWS, 3 * D_SZ, D_SZ);
        mattn_kernel<<<(SEQ / 64) * NB * NH, 256, 0, stream>>>(qkvb_a, attb);
        // x = attb @ proj_w + b + x   (64x64x64: 512 blk = 2/CU)
        mgemm_kernel<64, 64, 64, 2, true, false, true, false, false, false, false>
            <<<dim3(D_SZ / 64, M_ROWS / 64), 256, 0, stream>>>(
                attb, wp + (size_t)l * D_SZ * D_SZ, projb + (size_t)l * D_SZ,
                x, x, M_ROWS, D_SZ, D_SZ);
        ln_kernel<<<M_ROWS / 4, 256, 0, stream>>>(x, ln2w + l * D_SZ, ln2b + l * D_SZ, hb);
        // ffnb = gelu(hb @ fc1_w + b)   [4096,2048] bf16  (64x128x64: 1024 blk)
        mgemm_kernel<64, 128, 64, 2, true, true, false, true, false, false, false>
            <<<dim3(4 * D_SZ / 128, M_ROWS / 64), 256, 0, stream>>>(
                hb, w1 + (size_t)l * 4 * D_SZ * D_SZ, fc1b + (size_t)l * 4 * D_SZ,
                nullptr, ffnb, M_ROWS, 4 * D_SZ, D_SZ);
        // x = ffnb @ fc2_w + b + x   (64x64x64: 512 blk = 2/CU, 32 K-steps)
        mgemm_kernel<64, 64, 64, 2, true, false, true, false, false, false, false>
            <<<dim3(D_SZ / 64, M_ROWS / 64), 256, 0, stream>>>(
                ffnb, w2 + (size_t)l * D_SZ * 4 * D_SZ, fc2b + (size_t)l * D_SZ,
                x, x, M_ROWS, D_SZ, 4 * D_SZ);
    }

    // merged final-LN + tok conv (1 dispatch instead of 2)
    lnconv_kernel<<<M_ROWS / 4 + V_SZ * D_SZ / 4 / 256, 256, 0, stream>>>(
        x, lnfw, lnfb, hb, tok, tokb);
    // out = hb @ tokb^T   [4096,32000] f32   (128x128x32; grid M-fastest +
    // XCD-chunk swizzle: each XCD owns 1000 contiguous tiles = ~31 B-panels;
    // scalar NT stores, row-outer order)
    mgemm_kernel<128, 128, 32, 2, false, false, false, false, true, true, true>
        <<<dim3(M_ROWS / 128, V_SZ / 128), 256, 0, stream>>>(
            hb, tokb, nullptr, nullptr, out, M_ROWS, V_SZ, D_SZ);
}

// Round 17
// 693.456 us; speedup vs baseline: 1.0373x; 1.0373x over previous
//
#include <hip/hip_runtime.h>
#include <math.h>

// Problem constants (MinimalGPT)
#define V_SZ 32000
#define D_SZ 512
#define NL 4
#define NH 8
#define SEQ 2048
#define HD 64
#define NB 2
#define M_ROWS (NB * SEQ)   // 4096

typedef __attribute__((ext_vector_type(8))) short bf16x8;
typedef __attribute__((ext_vector_type(4))) float f32x4;
typedef __attribute__((ext_vector_type(4))) unsigned short u16x4;

__device__ __forceinline__ unsigned short f2bf(float f) {
    unsigned int x = __float_as_uint(f);
    unsigned int r = (x + 0x7FFFu + ((x >> 16) & 1u)) >> 16;
    return (unsigned short)r;
}

__device__ __forceinline__ float gelu_f(float x) {
    return 0.5f * x * (1.0f + erff(x * 0.70710678118654752f));
}

__device__ __forceinline__ void gload16(const void* g, void* l) {
    __builtin_amdgcn_global_load_lds(
        (const __attribute__((address_space(1))) void*)g,
        (__attribute__((address_space(3))) void*)l, 16, 0, 0);
}

// ---------------- merged prep: 4x tconv (weights->bf16 [N,K]) + embedding -----
__device__ __forceinline__ void tconv_body(
    const float* __restrict__ in, unsigned short* __restrict__ out,
    int K, int N, int lin, float (*t)[33]) {
    int nx = N / 32, ny = K / 32;
    int bx = lin % nx;
    int r2 = lin / nx;
    int by = r2 % ny;
    int l = r2 / ny;
    in += (size_t)l * K * N;
    out += (size_t)l * N * K;
    int n0 = bx * 32, k0 = by * 32;
    int tx = threadIdx.x & 31, ty = threadIdx.x >> 5;
    #pragma unroll
    for (int p = 0; p < 4; p++) {
        int k = ty + p * 8;
        t[k][tx] = in[(size_t)(k0 + k) * N + n0 + tx];
    }
    __syncthreads();
    #pragma unroll
    for (int p = 0; p < 4; p++) {
        int n = ty + p * 8;
        out[(size_t)(n0 + n) * K + k0 + tx] = f2bf(t[tx][n]);
    }
}

#define TCQ 3072   // (1536/32)*(512/32)*4
#define TCP 1024   // (512/32)*(512/32)*4
#define TC1 4096   // (2048/32)*(512/32)*4
#define TC2 4096   // (512/32)*(2048/32)*4
#define EMB 8192   // 4096*512/256

__global__ __launch_bounds__(256) void prep_kernel(
    const float* __restrict__ qkvw, const float* __restrict__ projw,
    const float* __restrict__ fc1w, const float* __restrict__ fc2w,
    const int* __restrict__ ids, const float* __restrict__ tok,
    const float* __restrict__ pos,
    unsigned short* __restrict__ wq, unsigned short* __restrict__ wp,
    unsigned short* __restrict__ w1, unsigned short* __restrict__ w2,
    float* __restrict__ x) {
    __shared__ float t[32][33];
    int b = blockIdx.x;
    if (b < TCQ) { tconv_body(qkvw, wq, D_SZ, 3 * D_SZ, b, t); return; }
    b -= TCQ;
    if (b < TCP) { tconv_body(projw, wp, D_SZ, D_SZ, b, t); return; }
    b -= TCP;
    if (b < TC1) { tconv_body(fc1w, w1, D_SZ, 4 * D_SZ, b, t); return; }
    b -= TC1;
    if (b < TC2) { tconv_body(fc2w, w2, 4 * D_SZ, D_SZ, b, t); return; }
    b -= TC2;
    // embedding
    int idx = b * 256 + threadIdx.x;
    int row = idx >> 9;
    int d = idx & 511;
    int tt = row & (SEQ - 1);
    x[idx] = tok[(size_t)ids[row] * D_SZ + d] + pos[(size_t)tt * D_SZ + d];
}

// ---------------- layernorm over last dim (512) -> bf16 out --------------------
// wave-per-row: 4 waves/block, one row per wave, pure shfl reduce.
__global__ __launch_bounds__(256) void ln_kernel(
    const float* __restrict__ x, const float* __restrict__ w,
    const float* __restrict__ b, unsigned short* __restrict__ out) {
    int row = blockIdx.x * 4 + (threadIdx.x >> 6);
    int lane = threadIdx.x & 63;
    const float* xr = x + (size_t)row * D_SZ + lane * 8;
    float4 v0 = *(const float4*)xr;
    float4 v1 = *(const float4*)(xr + 4);
    float s = ((v0.x + v0.y) + (v0.z + v0.w)) + ((v1.x + v1.y) + (v1.z + v1.w));
    #pragma unroll
    for (int off = 1; off < 64; off <<= 1) s += __shfl_xor(s, off);
    float mu = s * (1.0f / 512.0f);
    float d0 = v0.x - mu, d1 = v0.y - mu, d2 = v0.z - mu, d3 = v0.w - mu;
    float d4 = v1.x - mu, d5 = v1.y - mu, d6 = v1.z - mu, d7 = v1.w - mu;
    float q = ((d0 * d0 + d1 * d1) + (d2 * d2 + d3 * d3)) +
              ((d4 * d4 + d5 * d5) + (d6 * d6 + d7 * d7));
    #pragma unroll
    for (int off = 1; off < 64; off <<= 1) q += __shfl_xor(q, off);
    float rs = rsqrtf(q * (1.0f / 512.0f) + 1e-5f);
    const float* wp = w + lane * 8;
    const float* bp = b + lane * 8;
    float4 w0 = *(const float4*)wp, w1 = *(const float4*)(wp + 4);
    float4 b0 = *(const float4*)bp, b1 = *(const float4*)(bp + 4);
    uint4 pk;
    pk.x = (unsigned)f2bf(d0 * rs * w0.x + b0.x) | ((unsigned)f2bf(d1 * rs * w0.y + b0.y) << 16);
    pk.y = (unsigned)f2bf(d2 * rs * w0.z + b0.z) | ((unsigned)f2bf(d3 * rs * w0.w + b0.w) << 16);
    pk.z = (unsigned)f2bf(d4 * rs * w1.x + b1.x) | ((unsigned)f2bf(d5 * rs * w1.y + b1.y) << 16);
    pk.w = (unsigned)f2bf(d6 * rs * w1.z + b1.z) | ((unsigned)f2bf(d7 * rs * w1.w + b1.w) << 16);
    *(uint4*)(out + (size_t)row * D_SZ + lane * 8) = pk;
}

// ---------------- merged final-LN (wave-per-row) + tok_emb conv (NT) ----------
__global__ __launch_bounds__(256) void lnconv_kernel(
    const float* __restrict__ x, const float* __restrict__ w,
    const float* __restrict__ b, unsigned short* __restrict__ out,
    const float* __restrict__ tok, unsigned short* __restrict__ tokb) {
    int blk = blockIdx.x;
    if (blk < M_ROWS / 4) {
        int row = blk * 4 + (threadIdx.x >> 6);
        int lane = threadIdx.x & 63;
        const float* xr = x + (size_t)row * D_SZ + lane * 8;
        float4 v0 = *(const float4*)xr;
        float4 v1 = *(const float4*)(xr + 4);
        float s = ((v0.x + v0.y) + (v0.z + v0.w)) + ((v1.x + v1.y) + (v1.z + v1.w));
        #pragma unroll
        for (int off = 1; off < 64; off <<= 1) s += __shfl_xor(s, off);
        float mu = s * (1.0f / 512.0f);
        float d0 = v0.x - mu, d1 = v0.y - mu, d2 = v0.z - mu, d3 = v0.w - mu;
        float d4 = v1.x - mu, d5 = v1.y - mu, d6 = v1.z - mu, d7 = v1.w - mu;
        float q = ((d0 * d0 + d1 * d1) + (d2 * d2 + d3 * d3)) +
                  ((d4 * d4 + d5 * d5) + (d6 * d6 + d7 * d7));
        #pragma unroll
        for (int off = 1; off < 64; off <<= 1) q += __shfl_xor(q, off);
        float rs = rsqrtf(q * (1.0f / 512.0f) + 1e-5f);
        const float* wp = w + lane * 8;
        const float* bp = b + lane * 8;
        float4 w0 = *(const float4*)wp, w1 = *(const float4*)(wp + 4);
        float4 b0 = *(const float4*)bp, b1 = *(const float4*)(bp + 4);
        uint4 pk;
        pk.x = (unsigned)f2bf(d0 * rs * w0.x + b0.x) | ((unsigned)f2bf(d1 * rs * w0.y + b0.y) << 16);
        pk.y = (unsigned)f2bf(d2 * rs * w0.z + b0.z) | ((unsigned)f2bf(d3 * rs * w0.w + b0.w) << 16);
        pk.z = (unsigned)f2bf(d4 * rs * w1.x + b1.x) | ((unsigned)f2bf(d5 * rs * w1.y + b1.y) << 16);
        pk.w = (unsigned)f2bf(d6 * rs * w1.z + b1.z) | ((unsigned)f2bf(d7 * rs * w1.w + b1.w) << 16);
        *(uint4*)(out + (size_t)row * D_SZ + lane * 8) = pk;
    } else {
        int i = (blk - M_ROWS / 4) * 256 + threadIdx.x;
        float4 v = ((const float4*)tok)[i];
        u16x4 u;
        u.x = f2bf(v.x); u.y = f2bf(v.y); u.z = f2bf(v.z); u.w = f2bf(v.w);
        __builtin_nontemporal_store(u, (u16x4*)tokb + i);
    }
}

// ---------------- MFMA flash attention (bf16 in/out, f32 softmax) --------------
// R12 version: T14 reg prefetch; Q pre-scaled by 0.125 (exact pow2).
__global__ __launch_bounds__(256) void mattn_kernel(
    const unsigned short* __restrict__ qkv, unsigned short* __restrict__ att) {
    __shared__ unsigned short Ks[64][72];       // [key][dim], +8 pad
    __shared__ unsigned short Vt[64][72];       // [dim][key], block-swizzled
    __shared__ unsigned short Ps[4][16][72];    // per-wave [q][key]
    int id = blockIdx.x;
    int bh = id >> 5;
    int jraw = id & 31;
    int jt = (id < 256) ? jraw : (31 - jraw);   // heavy/light pairing
    int b = bh >> 3, h = bh & 7;
    int tid = threadIdx.x, lane = tid & 63, wid = tid >> 6;
    int q15 = lane & 15, g = lane >> 4;
    int qglob = jt * 64 + wid * 16 + q15;       // this lane's q row (in batch b)
    const unsigned short* base = qkv + (size_t)b * SEQ * (3 * D_SZ);
    const unsigned short* qptr = base + (size_t)qglob * (3 * D_SZ) + h * HD;
    bf16x8 qf0 = *(const bf16x8*)(qptr + g * 8);
    bf16x8 qf1 = *(const bf16x8*)(qptr + 32 + g * 8);
    // pre-scale Q by 1/sqrt(HD)=0.125 (exact for bf16: power-of-2)
    #pragma unroll
    for (int i = 0; i < 8; i++) {
        qf0[i] = (short)f2bf(
            __uint_as_float(((unsigned)(unsigned short)qf0[i]) << 16) * 0.125f);
        qf1[i] = (short)f2bf(
            __uint_as_float(((unsigned)(unsigned short)qf1[i]) << 16) * 0.125f);
    }

    f32x4 OT[4];
    f32x4 zero = {0.0f, 0.0f, 0.0f, 0.0f};
    #pragma unroll
    for (int n = 0; n < 4; n++) OT[n] = zero;
    float mrun = -1e30f, lrun = 0.0f;

    // prefetch lanes/addresses
    int krow = tid >> 3, kprt = tid & 7;        // K: rows krow and 32+krow
    const unsigned short* kbase = base + D_SZ + h * HD + kprt * 8;
    const unsigned short* vbase = base + 2 * D_SZ + h * HD + kprt * 8;
    bf16x8 kp0, kp1, vp0, vp1;

    // prologue: load tile 0 into regs
    kp0 = *(const bf16x8*)(kbase + (size_t)krow * (3 * D_SZ));
    kp1 = *(const bf16x8*)(kbase + (size_t)(32 + krow) * (3 * D_SZ));
    vp0 = *(const bf16x8*)(vbase + (size_t)(2 * krow) * (3 * D_SZ));
    vp1 = *(const bf16x8*)(vbase + (size_t)(2 * krow + 1) * (3 * D_SZ));

    int nt = jt + 1;
    for (int st = 0; st < nt; st++) {
        int s0 = st * 64;
        __syncthreads();                        // prev-tile consumers done
        // write prefetched K [key][dim]
        *(bf16x8*)&Ks[krow][kprt * 8] = kp0;
        *(bf16x8*)&Ks[32 + krow][kprt * 8] = kp1;
        // write prefetched V^T [dim][key] with block swizzle
        {
            int col = (((krow >> 2) ^ kprt) << 3) | ((2 * krow) & 7);
            #pragma unroll
            for (int i = 0; i < 8; i++) {
                int d = kprt * 8 + i;
                unsigned w = (unsigned)(unsigned short)vp0[i]
                           | ((unsigned)(unsigned short)vp1[i] << 16);
                *(unsigned*)&Vt[d][col] = w;
            }
        }
        __syncthreads();
        // issue next-tile loads (latency overlaps compute below)
        if (st + 1 < nt) {
            int s1 = s0 + 64;
            kp0 = *(const bf16x8*)(kbase + (size_t)(s1 + krow) * (3 * D_SZ));
            kp1 = *(const bf16x8*)(kbase + (size_t)(s1 + 32 + krow) * (3 * D_SZ));
            vp0 = *(const bf16x8*)(vbase + (size_t)(s1 + 2 * krow) * (3 * D_SZ));
            vp1 = *(const bf16x8*)(vbase + (size_t)(s1 + 2 * krow + 1) * (3 * D_SZ));
        }

        // S^T = K @ Q^T : frag n covers keys n*16..+15 (Q pre-scaled)
        f32x4 S[4];
        #pragma unroll
        for (int n = 0; n < 4; n++) S[n] = zero;
        #pragma unroll
        for (int n = 0; n < 4; n++)
            S[n] = __builtin_amdgcn_mfma_f32_16x16x32_bf16(
                *(const bf16x8*)&Ks[n * 16 + q15][g * 8], qf0, S[n], 0, 0, 0);
        #pragma unroll
        for (int n = 0; n < 4; n++)
            S[n] = __builtin_amdgcn_mfma_f32_16x16x32_bf16(
                *(const bf16x8*)&Ks[n * 16 + q15][32 + g * 8], qf1, S[n], 0, 0, 0);

        // softmax (per lane: 16 scores of q-row qglob; keys n*16+g*4+r)
        bool diag = (st == jt);
        float sm[4][4];
        float mloc = -1e30f;
        #pragma unroll
        for (int n = 0; n < 4; n++)
            #pragma unroll
            for (int r = 0; r < 4; r++) {
                float s = S[n][r];
                if (diag && (s0 + n * 16 + g * 4 + r) > qglob) s = -1e30f;
                sm[n][r] = s;
                mloc = fmaxf(mloc, s);
            }
        mloc = fmaxf(mloc, __shfl_xor(mloc, 16));
        mloc = fmaxf(mloc, __shfl_xor(mloc, 32));
        float mnew = fmaxf(mrun, mloc);
        float corr = __expf(mrun - mnew);
        lrun *= corr;
        #pragma unroll
        for (int n = 0; n < 4; n++) OT[n] *= corr;
        float lsum = 0.0f;
        #pragma unroll
        for (int n = 0; n < 4; n++) {
            float p0 = __expf(sm[n][0] - mnew);
            float p1 = __expf(sm[n][1] - mnew);
            float p2 = __expf(sm[n][2] - mnew);
            float p3 = __expf(sm[n][3] - mnew);
            lsum += (p0 + p1) + (p2 + p3);
            uint2 pk;
            pk.x = (unsigned)f2bf(p0) | ((unsigned)f2bf(p1) << 16);
            pk.y = (unsigned)f2bf(p2) | ((unsigned)f2bf(p3) << 16);
            *(uint2*)&Ps[wid][q15][n * 16 + g * 4] = pk;
        }
        lsum += __shfl_xor(lsum, 16);
        lsum += __shfl_xor(lsum, 32);
        lrun += lsum;
        mrun = mnew;

        // O^T += V^T @ P^T : frag n covers dims n*16..+15
        #pragma unroll
        for (int ks = 0; ks < 2; ks++) {
            bf16x8 bp = *(const bf16x8*)&Ps[wid][q15][ks * 32 + g * 8];
            #pragma unroll
            for (int n = 0; n < 4; n++) {
                int d = n * 16 + q15;
                int col = (((ks * 4 + g) ^ ((d >> 3) & 7)) << 3);
                OT[n] = __builtin_amdgcn_mfma_f32_16x16x32_bf16(
                    *(const bf16x8*)&Vt[d][col], bp, OT[n], 0, 0, 0);
            }
        }
    }

    float inv = 1.0f / lrun;
    unsigned short* orow = att + ((size_t)(b * SEQ) + qglob) * D_SZ + h * HD;
    #pragma unroll
    for (int n = 0; n < 4; n++) {
        uint2 u;
        u.x = (unsigned)f2bf(OT[n][0] * inv) | ((unsigned)f2bf(OT[n][1] * inv) << 16);
        u.y = (unsigned)f2bf(OT[n][2] * inv) | ((unsigned)f2bf(OT[n][3] * inv) << 16);
        *(uint2*)(orow + n * 16 + g * 4) = u;
    }
}

// ---------------- bf16 MFMA GEMM: C = A[M,K] @ Bt[N,K]^T (+bias)(+gelu)(+resid)
// 2-phase double-buffered K-loop (session-best structure). SWAPXY: head grid
// sweeps M fastest (B-panel L2 locality, R5 win). NTC: non-temporal scalar
// C-stores, row-outer/col-inner order (R10+R12 verified). No XCD swizzle
// (R15: +25us — linear dispatch's natural round-robin cooperatively walks the
// same B-panel window across XCDs; chunking de-synchronizes it).
template <int BM, int BN, int BK, int WC, bool BIAS, bool GELU_, bool RESID,
          bool OUTBF, bool SWAPXY, bool NTC>
__global__ __launch_bounds__(256) void mgemm_kernel(
    const unsigned short* __restrict__ A,    // [M,K] bf16
    const unsigned short* __restrict__ Bt,   // [N,K] bf16
    const float* __restrict__ bias,
    const float* __restrict__ resid,
    void* __restrict__ Cv, int M, int N, int K) {
    constexpr int WR = 4 / WC;
    constexpr int WRM = BM / WR;
    constexpr int WCN = BN / WC;
    constexpr int FM = WRM / 16;
    constexpr int FN = WCN / 16;
    constexpr int CPR = BK / 8;            // 16B chunks per LDS row
    constexpr int LA = BM * CPR / 256;     // A chunks per thread
    constexpr int LB = BN * CPR / 256;     // B chunks per thread
    __shared__ __attribute__((aligned(16))) unsigned short As[2][BM][BK];
    __shared__ __attribute__((aligned(16))) unsigned short Bs[2][BN][BK];
    int tid = threadIdx.x;
    int lane = tid & 63;
    int wid = tid >> 6;
    int wr = wid / WC, wc = wid % WC;
    int m0 = (SWAPXY ? blockIdx.x : blockIdx.y) * BM;
    int n0 = (SWAPXY ? blockIdx.y : blockIdx.x) * BN;
    int r16 = lane & 15, kg = lane >> 4;

    f32x4 acc[FM][FN];
    f32x4 zero = {0.0f, 0.0f, 0.0f, 0.0f};
    #pragma unroll
    for (int m = 0; m < FM; m++)
        #pragma unroll
        for (int n = 0; n < FN; n++) acc[m][n] = zero;

    const unsigned short* Abase = A + (size_t)m0 * K;
    const unsigned short* Bbase = Bt + (size_t)n0 * K;

    // prologue: stage K-tile 0 into buffer 0
    #pragma unroll
    for (int i = 0; i < LA; i++) {
        int c = i * 256 + tid;
        gload16(Abase + (size_t)(c / CPR) * K + (c % CPR) * 8,
                &As[0][c / CPR][(c % CPR) * 8]);
    }
    #pragma unroll
    for (int i = 0; i < LB; i++) {
        int c = i * 256 + tid;
        gload16(Bbase + (size_t)(c / CPR) * K + (c % CPR) * 8,
                &Bs[0][c / CPR][(c % CPR) * 8]);
    }
    __syncthreads();

    unsigned short* a_cur = &As[0][0][0];
    unsigned short* a_nxt = &As[1][0][0];
    unsigned short* b_cur = &Bs[0][0][0];
    unsigned short* b_nxt = &Bs[1][0][0];

    for (int k0 = 0; k0 < K; k0 += BK) {
        // issue next-tile staging first (overlaps with current compute)
        if (k0 + BK < K) {
            #pragma unroll
            for (int i = 0; i < LA; i++) {
                int c = i * 256 + tid;
                gload16(Abase + (size_t)(c / CPR) * K + (k0 + BK) + (c % CPR) * 8,
                        a_nxt + c * 8);
            }
            #pragma unroll
            for (int i = 0; i < LB; i++) {
                int c = i * 256 + tid;
                gload16(Bbase + (size_t)(c / CPR) * K + (k0 + BK) + (c % CPR) * 8,
                        b_nxt + c * 8);
            }
        }
        #pragma unroll
        for (int kk = 0; kk < BK / 32; kk++) {
            bf16x8 af[FM], bfr[FN];
            #pragma unroll
            for (int m = 0; m < FM; m++)
                af[m] = *(const bf16x8*)&a_cur[(wr * WRM + m * 16 + r16) * BK +
                                               kk * 32 + kg * 8];
            #pragma unroll
            for (int n = 0; n < FN; n++)
                bfr[n] = *(const bf16x8*)&b_cur[(wc * WCN + n * 16 + r16) * BK +
                                                kk * 32 + kg * 8];
            #pragma unroll
            for (int m = 0; m < FM; m++)
                #pragma unroll
                for (int n = 0; n < FN; n++)
                    acc[m][n] = __builtin_amdgcn_mfma_f32_16x16x32_bf16(
                        af[m], bfr[n], acc[m][n], 0, 0, 0);
        }
        __syncthreads();   // vmcnt(0)+lgkmcnt(0) drain AFTER compute
        unsigned short* t;
        t = a_cur; a_cur = a_nxt; a_nxt = t;
        t = b_cur; b_cur = b_nxt; b_nxt = t;
    }

    // epilogue: row-outer / col-inner store order (write-combining friendly)
    float bvv[FN];
    #pragma unroll
    for (int n = 0; n < FN; n++)
        bvv[n] = BIAS ? bias[n0 + wc * WCN + n * 16 + r16] : 0.0f;
    #pragma unroll
    for (int m = 0; m < FM; m++) {
        int rb = m0 + wr * WRM + m * 16 + kg * 4;
        #pragma unroll
        for (int r = 0; r < 4; r++) {
            size_t rowoff = (size_t)(rb + r) * N;
            #pragma unroll
            for (int n = 0; n < FN; n++) {
                int col = n0 + wc * WCN + n * 16 + r16;
                float v = acc[m][n][r] + bvv[n];
                if (GELU_) v = gelu_f(v);
                if (RESID) v += resid[rowoff + col];
                if (OUTBF) {
                    ((unsigned short*)Cv)[rowoff + col] = f2bf(v);
                } else if (NTC) {
                    __builtin_nontemporal_store(v, (float*)Cv + rowoff + col);
                } else {
                    ((float*)Cv)[rowoff + col] = v;
                }
            }
        }
    }
}

extern "C" void kernel_launch(void* const* d_in, const int* in_sizes, int n_in,
                              void* d_out, int out_size, void* d_ws, size_t ws_size,
                              hipStream_t stream) {
    const int*   ids   = (const int*)d_in[0];
    const float* tok   = (const float*)d_in[1];
    const float* pos   = (const float*)d_in[2];
    const float* ln1w  = (const float*)d_in[3];
    const float* ln1b  = (const float*)d_in[4];
    const float* qkvw  = (const float*)d_in[5];
    const float* qkvb  = (const float*)d_in[6];
    const float* projw = (const float*)d_in[7];
    const float* projb = (const float*)d_in[8];
    const float* ln2w  = (const float*)d_in[9];
    const float* ln2b  = (const float*)d_in[10];
    const float* fc1w  = (const float*)d_in[11];
    const float* fc1b  = (const float*)d_in[12];
    const float* fc2w  = (const float*)d_in[13];
    const float* fc2b  = (const float*)d_in[14];
    const float* lnfw  = (const float*)d_in[15];
    const float* lnfb  = (const float*)d_in[16];
    float* out = (float*)d_out;

    // ws layout:
    float* x = (float*)d_ws;                                   // [4096,512] f32
    unsigned short* hb = (unsigned short*)(x + (size_t)M_ROWS * D_SZ);
    unsigned short* wq = hb + (size_t)M_ROWS * D_SZ;           // [4][1536,512]
    unsigned short* wp = wq + (size_t)NL * D_SZ * 3 * D_SZ;    // [4][512,512]
    unsigned short* w1 = wp + (size_t)NL * D_SZ * D_SZ;        // [4][2048,512]
    unsigned short* w2 = w1 + (size_t)NL * D_SZ * 4 * D_SZ;    // [4][512,2048]
    unsigned short* qkvb_a = w2 + (size_t)NL * 4 * D_SZ * D_SZ;// [4096,1536] bf16
    unsigned short* attb = qkvb_a + (size_t)M_ROWS * 3 * D_SZ; // [4096,512]
    unsigned short* ffnb = attb + (size_t)M_ROWS * D_SZ;       // [4096,2048]
    unsigned short* tokb = qkvb_a;   // [32000,512] aliases qkv+attb+ffnb (33.4MB)

    // merged prep: 4x weight tconv + embedding (1 dispatch instead of 5)
    prep_kernel<<<TCQ + TCP + TC1 + TC2 + EMB, 256, 0, stream>>>(
        qkvw, projw, fc1w, fc2w, ids, tok, pos, wq, wp, w1, w2, x);

    for (int l = 0; l < NL; l++) {
        ln_kernel<<<M_ROWS / 4, 256, 0, stream>>>(x, ln1w + l * D_SZ, ln1b + l * D_SZ, hb);
        // qkv = hb @ qkv_w + b   [4096,1536] bf16   (64x128x64: 768 blk = 3/CU)
        mgemm_kernel<64, 128, 64, 2, true, false, false, true, false, false>
            <<<dim3(3 * D_SZ / 128, M_ROWS / 64), 256, 0, stream>>>(
                hb, wq + (size_t)l * 3 * D_SZ * D_SZ, qkvb + (size_t)l * 3 * D_SZ,
                nullptr, qkvb_a, M_ROWS, 3 * D_SZ, D_SZ);
        mattn_kernel<<<(SEQ / 64) * NB * NH, 256, 0, stream>>>(qkvb_a, attb);
        // x = attb @ proj_w + b + x   (64x64x64: 512 blk = 2/CU)
        mgemm_kernel<64, 64, 64, 2, true, false, true, false, false, false>
            <<<dim3(D_SZ / 64, M_ROWS / 64), 256, 0, stream>>>(
                attb, wp + (size_t)l * D_SZ * D_SZ, projb + (size_t)l * D_SZ,
                x, x, M_ROWS, D_SZ, D_SZ);
        ln_kernel<<<M_ROWS / 4, 256, 0, stream>>>(x, ln2w + l * D_SZ, ln2b + l * D_SZ, hb);
        // ffnb = gelu(hb @ fc1_w + b)   [4096,2048] bf16  (64x128x64: 1024 blk)
        mgemm_kernel<64, 128, 64, 2, true, true, false, true, false, false>
            <<<dim3(4 * D_SZ / 128, M_ROWS / 64), 256, 0, stream>>>(
                hb, w1 + (size_t)l * 4 * D_SZ * D_SZ, fc1b + (size_t)l * 4 * D_SZ,
                nullptr, ffnb, M_ROWS, 4 * D_SZ, D_SZ);
        // x = ffnb @ fc2_w + b + x   (64x64x64: 512 blk = 2/CU, 32 K-steps)
        mgemm_kernel<64, 64, 64, 2, true, false, true, false, false, false>
            <<<dim3(D_SZ / 64, M_ROWS / 64), 256, 0, stream>>>(
                ffnb, w2 + (size_t)l * D_SZ * 4 * D_SZ, fc2b + (size_t)l * D_SZ,
                x, x, M_ROWS, D_SZ, 4 * D_SZ);
    }

    // merged final-LN + tok conv (1 dispatch instead of 2); tokb = qkvb_a
    lnconv_kernel<<<M_ROWS / 4 + V_SZ * D_SZ / 4 / 256, 256, 0, stream>>>(
        x, lnfw, lnfb, hb, tok, tokb);
    // out = hb @ tokb^T   [4096,32000] f32   (128x128x32; grid M-fastest:
    // consecutive blocks share B-panel; scalar NT stores, row-outer order)
    mgemm_kernel<128, 128, 32, 2, false, false, false, false, true, true>
        <<<dim3(M_ROWS / 128, V_SZ / 128), 256, 0, stream>>>(
            hb, tokb, nullptr, nullptr, out, M_ROWS, V_SZ, D_SZ);
}